// Round 1
// baseline (246.341 us; speedup 1.0000x reference)
//
#include <hip/hip_runtime.h>
#include <math.h>

#define BATCH 8
#define CH    256
#define H     128
#define W     128
#define HW    (H * W)          // 16384
#define OH    65
#define OW    65
#define NPIX  (OH * OW)        // 4225
#define CGRP  8                // channels per pool block (small -> more blocks/batch)
#define PBLK  17               // ceil(NPIX/256) pixel tiles
#define POOL_BLOCKS (PBLK * (CH / CGRP))   // 17*32 = 544 blocks per batch
#define NORM_BLOCKS 128                    // 4096 quads / 32 per block

// ---- norm phase: per-pixel channel L2 norm for ONE batch image ----
// block = 256 threads; 32 pixel-quads per block; thread (q = tid&31, ck = tid>>5)
// sums channels [ck*32, ck*32+32). Half-wave reads 32*16B = 512B contiguous.
__device__ __forceinline__ void norm_body(const float4* __restrict__ x4,
                                          float4* __restrict__ n4,
                                          int b, int blk, int tid) {
    __shared__ float4 part[8][32];
    const int q  = tid & 31;
    const int ck = tid >> 5;
    const int qg = blk * 32 + q;                      // quad within batch plane
    const float4* p = x4 + (size_t)(b * CH + ck * 32) * (HW / 4) + qg;
    float4 acc = {0.f, 0.f, 0.f, 0.f};
    #pragma unroll 16
    for (int c = 0; c < 32; ++c) {
        float4 v = p[(size_t)c * (HW / 4)];
        acc.x += v.x * v.x; acc.y += v.y * v.y;
        acc.z += v.z * v.z; acc.w += v.w * v.w;
    }
    part[ck][q] = acc;
    __syncthreads();
    if (tid < 32) {
        float4 s = part[0][tid];
        #pragma unroll
        for (int k = 1; k < 8; ++k) {
            float4 a = part[k][tid];
            s.x += a.x; s.y += a.y; s.z += a.z; s.w += a.w;
        }
        float4 r;
        r.x = sqrtf(s.x); r.y = sqrtf(s.y);
        r.z = sqrtf(s.z); r.w = sqrtf(s.w);
        n4[(size_t)b * (HW / 4) + blk * 32 + tid] = r;
    }
}

// ---- pool phase: softmax-weighted 3x3 stride-2 pooling for ONE batch image ----
// Identical arithmetic to the verified kernel; x[b] is L3-resident from the
// norm phase of the previous launch.
__device__ __forceinline__ void pool_body(const float* __restrict__ x,
                                          const float* __restrict__ n,
                                          float* __restrict__ out,
                                          int b, int pid) {
    const int cg = pid / PBLK;            // 0..31
    const int pt = pid - cg * PBLK;       // 0..16
    const int p  = pt * 256 + threadIdx.x;
    if (p >= NPIX) return;
    const int oh = p / OW;
    const int ow = p - oh * OW;
    const int iw0 = ow * 2 - 2;

    const float* nb = n + b * HW;

    // softmax weights over the 9 window norms (OOB -> n=0 in denom, weight 0 in numer)
    float nv[9];
    bool  val[9];
    float m = 0.0f;
    #pragma unroll
    for (int kh = 0; kh < 3; ++kh) {
        int ih = oh * 2 + kh - 2;
        bool vh = (unsigned)ih < (unsigned)H;
        #pragma unroll
        for (int kw = 0; kw < 3; ++kw) {
            int iw = iw0 + kw;
            int k = kh * 3 + kw;
            bool v = vh && ((unsigned)iw < (unsigned)W);
            val[k] = v;
            nv[k]  = v ? nb[ih * W + iw] : 0.0f;
            m = fmaxf(m, nv[k]);
        }
    }
    float denom = 0.0f;
    float wts[9];
    #pragma unroll
    for (int k = 0; k < 9; ++k) {
        float e = __expf(nv[k] - m);
        denom += e;
        wts[k] = val[k] ? e : 0.0f;
    }
    float inv = 1.0f / denom;
    #pragma unroll
    for (int k = 0; k < 9; ++k) wts[k] *= inv;

    // clamped (always-valid) offsets; weight=0 kills OOB contributions
    int off2[3], offs[3];
    const int iwa = iw0 < 0 ? 0 : iw0;              // even -> float2 aligned
    const int iwc = (iw0 + 2) > (W - 1) ? (W - 1) : (iw0 + 2);
    #pragma unroll
    for (int r = 0; r < 3; ++r) {
        int ih = oh * 2 + r - 2;
        int ihc = ih < 0 ? 0 : (ih > H - 1 ? H - 1 : ih);
        off2[r] = ihc * W + iwa;
        offs[r] = ihc * W + iwc;
    }

    const float* xb = x + (size_t)(b * CH + cg * CGRP) * HW;
    float*       ob = out + (size_t)(b * CH + cg * CGRP) * NPIX + p;

    #pragma unroll
    for (int c = 0; c < CGRP; ++c) {
        const float* xc = xb + (size_t)c * HW;
        float acc = 0.f;
        #pragma unroll
        for (int r = 0; r < 3; ++r) {
            float2 v2 = *(const float2*)(xc + off2[r]);
            float  vs = xc[offs[r]];
            acc += wts[r * 3 + 0] * v2.x + wts[r * 3 + 1] * v2.y + wts[r * 3 + 2] * vs;
        }
        ob[(size_t)c * NPIX] = acc;
    }
}

// ---- uber kernel: co-schedules norm(b_norm) [HBM-bound] with pool(b_pool)
// [L3-bound]. Norm blocks first so the HBM stream (the long pole) starts
// immediately; pool(b) depends on norm(b) from the PREVIOUS launch, enforced
// by the kernel boundary. norm(b+1) in the same launch is independent of
// pool(b), so HBM prefetch of the next batch overlaps L3 drain of this one.
__global__ __launch_bounds__(256)
void stage_kernel(const float* __restrict__ x, float* __restrict__ nbuf,
                  float* __restrict__ out, int b_norm, int b_pool,
                  int n_norm_blocks) {
    if ((int)blockIdx.x < n_norm_blocks) {
        norm_body((const float4*)x, (float4*)nbuf, b_norm, blockIdx.x, threadIdx.x);
    } else {
        pool_body(x, nbuf, out, b_pool, blockIdx.x - n_norm_blocks);
    }
}

extern "C" void kernel_launch(void* const* d_in, const int* in_sizes, int n_in,
                              void* d_out, int out_size, void* d_ws, size_t ws_size,
                              hipStream_t stream) {
    const float* x = (const float*)d_in[0];
    float* out = (float*)d_out;
    float* nbuf = (float*)d_ws;  // BATCH*H*W floats = 512 KB

    // prologue: norm(0) only
    stage_kernel<<<NORM_BLOCKS, 256, 0, stream>>>(x, nbuf, out, 0, 0, NORM_BLOCKS);
    // steady state: norm(b+1) || pool(b)
    for (int b = 0; b < BATCH - 1; ++b) {
        stage_kernel<<<NORM_BLOCKS + POOL_BLOCKS, 256, 0, stream>>>(
            x, nbuf, out, b + 1, b, NORM_BLOCKS);
    }
    // epilogue: pool(7) only
    stage_kernel<<<POOL_BLOCKS, 256, 0, stream>>>(x, nbuf, out, 0, BATCH - 1, 0);
}